// Round 2
// baseline (5046.890 us; speedup 1.0000x reference)
//
#include <hip/hip_runtime.h>

#define Tn 1024
#define Fn 64
#define Un 256
#define Gn 1024
#define AS 328       // padded A row stride (ushorts)
#define THREADS 256
#define NB 128       // lstm blocks

typedef __attribute__((ext_vector_type(8))) short bf16x8;
typedef __attribute__((ext_vector_type(8))) unsigned short ushort8;
typedef __attribute__((ext_vector_type(4))) float f32x4;
typedef unsigned long long u64;

// ws layout (bytes):
//   [0, 4096)            : int hdr — [0]=dtype flag, [1]=launch counter,
//                          [32..159]=per-block XCD slots (launch-tagged)
//   [WS_XCHG, +1048576)  : SLOW mailbox — NB x 2 parity x 1024 tagged u32,
//                          agent-scope atomics (the proven LLC path)
//   [WS_BP,  +655360)    : packed weights Bp
//   [WS_XF,  +1048576)   : FAST mailbox — same layout, plain stores /
//                          sc0 loads (same-XCD shared-L2 path)
#define WS_XCHG 4096
#define WS_BP   (WS_XCHG + NB*2*4096)
#define WS_XF   (WS_BP + 655360)

__device__ __forceinline__ float bf2f(unsigned short u){
  union { unsigned int i; float f; } v; v.i = ((unsigned int)u) << 16; return v.f;
}
__device__ __forceinline__ unsigned short f2bf(float f){
  unsigned int u = __float_as_uint(f);
  u += 0x7FFFu + ((u >> 16) & 1u);
  return (unsigned short)(u >> 16);
}
__device__ __forceinline__ float load_f(const void* p, long idx, int isf32){
  if (isf32) return ((const float*)p)[idx];
  return bf2f(((const unsigned short*)p)[idx]);
}
__device__ __forceinline__ float sigm(float x){ return 1.0f / (1.0f + __expf(-x)); }
__device__ __forceinline__ float tanh_f(float x){ return 2.0f * sigm(2.0f * x) - 1.0f; }

__device__ __forceinline__ u64 ld_a64(const u64* p){
  return __hip_atomic_load(p, __ATOMIC_RELAXED, __HIP_MEMORY_SCOPE_AGENT);
}
__device__ __forceinline__ int ok64(u64 v, unsigned int need){
  return (int)(((unsigned int)v & 0xFFFFu) == need) &
         (int)(((unsigned int)(v >> 32) & 0xFFFFu) == need);
}

// ---------------------------------------------------------------------------
// Fast-mailbox poll primitives: sc0 loads bypass the per-CU L1 and are served
// by the XCD-shared L2. Used ONLY as an accelerator — liveness never depends
// on them (every 16th spin iteration polls the slow mailbox agent-scope).
__device__ __forceinline__ void ld6_issue_l2(const u64* a0, const u64* a1,
                                             const u64* a2, u64* pw){
  asm volatile(
    "global_load_dwordx2 %0, %6, off sc0\n\t"
    "global_load_dwordx2 %1, %6, off offset:8 sc0\n\t"
    "global_load_dwordx2 %2, %7, off sc0\n\t"
    "global_load_dwordx2 %3, %7, off offset:8 sc0\n\t"
    "global_load_dwordx2 %4, %8, off sc0\n\t"
    "global_load_dwordx2 %5, %8, off offset:8 sc0"
    : "=&v"(pw[0]), "=&v"(pw[1]), "=&v"(pw[2]),
      "=&v"(pw[3]), "=&v"(pw[4]), "=&v"(pw[5])
    : "v"(a0), "v"(a1), "v"(a2)
    : "memory");
}
__device__ __forceinline__ void ld6_wait_l2(const u64* a0, const u64* a1,
                                            const u64* a2, u64* pw){
  asm volatile(
    "global_load_dwordx2 %0, %6, off sc0\n\t"
    "global_load_dwordx2 %1, %6, off offset:8 sc0\n\t"
    "global_load_dwordx2 %2, %7, off sc0\n\t"
    "global_load_dwordx2 %3, %7, off offset:8 sc0\n\t"
    "global_load_dwordx2 %4, %8, off sc0\n\t"
    "global_load_dwordx2 %5, %8, off offset:8 sc0\n\t"
    "s_waitcnt vmcnt(0)"
    : "=&v"(pw[0]), "=&v"(pw[1]), "=&v"(pw[2]),
      "=&v"(pw[3]), "=&v"(pw[4]), "=&v"(pw[5])
    : "v"(a0), "v"(a1), "v"(a2)
    : "memory");
}
// wait with the polled words as tied operands: the tag checks become
// data-dependent on this asm, so the compiler cannot hoist them above it.
__device__ __forceinline__ void vm_wait_pw(u64* pw){
  asm volatile("s_waitcnt vmcnt(0)"
    : "+v"(pw[0]), "+v"(pw[1]), "+v"(pw[2]),
      "+v"(pw[3]), "+v"(pw[4]), "+v"(pw[5]));
}

#define OK6 (ok64(pw[0], need) & ok64(pw[1], need) & ok64(pw[2], need) & \
             ok64(pw[3], need) & ok64(pw[4], need) & ok64(pw[5], need))

// ---------------------------------------------------------------------------
__global__ void init_k(const void* x, int* wsi){
  int tid = threadIdx.x;
  if (tid < 64){
    int cnt = 0;
    for (int s2 = 0; s2 < 4; ++s2){
      float v = bf2f(((const unsigned short*)x)[tid + 64*s2]);
      if (!(fabsf(v) <= 100.0f)) cnt++;
    }
    for (int off = 32; off > 0; off >>= 1) cnt += __shfl_down(cnt, off);
    if (tid == 0) wsi[0] = (cnt > 32) ? 1 : 0;   // 1 => inputs are fp32
  }
  if (tid == 0) wsi[1] = wsi[1] + 1;   // launch counter (graph replays too)
  if (tid < NB) wsi[32 + tid] = 0;     // hygiene-zero XCD slots
}

// ---------------------------------------------------------------------------
// pack [Uh; W] (K=320 x 1024) into B-fragment order. 4-way split permutation:
//   packed n: s=n>>8, w=(n>>6)&3, g=(n>>4)&3, ul=n&15
//   -> orig col = g*256 + s*64 + w*16 + ul
__global__ void reformat_w(const void* Uh, const void* W, unsigned short* Bp, const int* dt){
  int isf32 = *dt;
  int gidx = blockIdx.x * blockDim.x + threadIdx.x;
  if (gidx >= 40960) return;
  int kt  = gidx >> 12;
  int rem = gidx & 4095;
  int n   = rem >> 2;
  int q   = rem & 3;
  int s   = n >> 8;
  int w   = (n >> 6) & 3;
  int g   = (n >> 4) & 3;
  int ul  = n & 15;
  int col = g*256 + s*64 + w*16 + ul;
  unsigned short vals[8];
  #pragma unroll
  for (int j = 0; j < 8; ++j){
    int k = kt*32 + q*8 + j;
    float v = (k < Un) ? load_f(Uh, (long)k*Gn + col, isf32)
                       : load_f(W,  (long)(k-Un)*Gn + col, isf32);
    vals[j] = f2bf(v);
  }
  *(ushort8*)(Bp + (long)gidx * 8) = *(ushort8*)vals;
}

// ---------------------------------------------------------------------------
// Persistent LSTM, 128 blocks x 256 threads.
// XCD-clustered mapping: group g = bid&31, slice s = bid>>5, so a group's four
// blocks {g, g+32, g+64, g+96} are congruent mod 8 — same XCD under
// round-robin dispatch. Runtime consensus (HW_REG_XCC_ID, launch-tagged)
// selects the protocol; co-located groups exchange h through the shared
// per-XCD L2 (plain store + sc0 load), others use the proven agent path.
// Liveness never depends on the fast path (periodic agent polls).
__global__ __launch_bounds__(THREADS, 1) void lstm_k(
    const void* x, const void* bvec, const void* dense_w, const void* dense_b,
    const unsigned short* Bp, int* hdr, unsigned int* xchg, unsigned int* xf,
    void* out)
{
  __shared__ __align__(16) unsigned short A_s[2][16*AS];
  __shared__ float outv[16];
  __shared__ int proto_s;

  const int isf32 = hdr[0];
  const unsigned int Lid = ((unsigned int)hdr[1]) & 0xFFFFu;
  const int tid = threadIdx.x;
  const int w   = tid >> 6;
  const int l   = tid & 63;
  const int l15 = l & 15;
  const int q   = l >> 4;
  const int g   = blockIdx.x & 31;   // group (same-XCD cluster under RR)
  const int s   = blockIdx.x >> 5;   // slice

  // publish own physical XCD id, tagged with this launch's id
  int* slots = hdr + 32;
  if (tid == 0){
    unsigned int xcc;
    asm volatile("s_getreg_b32 %0, hwreg(HW_REG_XCC_ID)" : "=s"(xcc));
    __hip_atomic_store(&slots[blockIdx.x], (int)((Lid << 16) | (xcc & 0xFFu)),
                       __ATOMIC_RELAXED, __HIP_MEMORY_SCOPE_AGENT);
  }

  int plist[3];
  #pragma unroll
  for (int j = 0; j < 3; ++j) plist[j] = j + (j >= s ? 1 : 0);

  // ---- weights into registers ----
  int ktp[10];
  ktp[0] = 2*s; ktp[1] = 2*s + 1; ktp[2] = 8; ktp[3] = 9;
  #pragma unroll
  for (int j = 0; j < 3; ++j){ ktp[4+2*j] = 2*plist[j]; ktp[5+2*j] = 2*plist[j] + 1; }

  const char* Bb = (const char*)Bp + (long)(l15*64 + q*16);
  const int nb = s*256 + w*64;
  bf16x8 wfrag[10][4];
  #pragma unroll
  for (int i = 0; i < 10; ++i){
    #pragma unroll
    for (int gg = 0; gg < 4; ++gg)
      wfrag[i][gg] = *(const bf16x8*)(Bb + (long)(ktp[i]*1024 + nb + gg*16)*64);
  }

  // zero h region of buffer 0
  for (int i = tid; i < 16*Un; i += THREADS)
    A_s[0][(i >> 8)*AS + (i & 255)] = 0;

  // x_0 -> buffer 0 cols [256,320)
  if (tid < 128){
    int m = tid >> 3, ch = tid & 7;
    long src = ((long)(g*16 + m)*Tn + 0)*Fn + ch*8;
    unsigned short v[8];
    if (isf32){ for (int j = 0; j < 8; ++j) v[j] = f2bf(((const float*)x)[src + j]); }
    else      { *(ushort8*)v = *(const ushort8*)((const unsigned short*)x + src); }
    *(ushort8*)&A_s[0][m*AS + Un + ch*8] = *(ushort8*)v;
  }

  const int u_loc = w*16 + l15;
  float bias[4];
  #pragma unroll
  for (int gg = 0; gg < 4; ++gg) bias[gg] = load_f(bvec, gg*256 + s*64 + u_loc, isf32);

  float c[4] = {0.f, 0.f, 0.f, 0.f};
  unsigned int* xc_slow = xchg + (size_t)(g*4 + s) * 2048;
  unsigned int* xc_fast = xf   + (size_t)(g*4 + s) * 2048;

  // per-thread partner poll addresses (parity offset applied per step)
  const u64* pas[3];
  const u64* paf[3];
  #pragma unroll
  for (int j = 0; j < 3; ++j){
    pas[j] = (const u64*)(xchg + (size_t)((g*4 + plist[j])*2)*1024) + tid*2;
    paf[j] = (const u64*)(xf   + (size_t)((g*4 + plist[j])*2)*1024) + tid*2;
  }

  // ---- XCD consensus: all four group members must agree (launch-tagged) ----
  if (tid == 0){
    int v0 = 0, ok = 1;
    #pragma unroll
    for (int m = 0; m < 4; ++m){
      int val;
      do {
        val = __hip_atomic_load(&slots[(m << 5) | g],
                                __ATOMIC_RELAXED, __HIP_MEMORY_SCOPE_AGENT);
      } while (((unsigned int)val >> 16) != Lid);
      if (m == 0) v0 = val; else ok &= (int)(val == v0);
    }
    proto_s = ok;   // 1 => all four blocks on one XCD => L2 (sc0) exchange
  }

  __syncthreads();
  const int fast = proto_s;

  for (int t = 0; t < Tn; ++t){
    const int buf = t & 1, nbuf = buf ^ 1;
    const size_t po = (size_t)buf * 512;   // parity offset in u64s
    const u64* sa0 = pas[0] + po;
    const u64* sa1 = pas[1] + po;
    const u64* sa2 = pas[2] + po;
    const u64* fa0 = paf[0] + po;
    const u64* fa1 = paf[1] + po;
    const u64* fa2 = paf[2] + po;

    // (1) x_{t+1} into regs
    unsigned short xv[8];
    if (tid < 128 && (t+1) < Tn){
      int m = tid >> 3, ch = tid & 7;
      long src = ((long)(g*16 + m)*Tn + (t+1))*Fn + ch*8;
      if (isf32){ for (int j = 0; j < 8; ++j) xv[j] = f2bf(((const float*)x)[src + j]); }
      else      { *(ushort8*)xv = *(const ushort8*)((const unsigned short*)x + src); }
    }

    // (1b) PRE-ISSUE all six partner tag-loads (fly under the MFMA phase)
    u64 pw[6];
    if (t > 0){
      if (fast){
        ld6_issue_l2(fa0, fa1, fa2, pw);
      } else {
        pw[0] = ld_a64(sa0);  pw[1] = ld_a64(sa0 + 1);
        pw[2] = ld_a64(sa1);  pw[3] = ld_a64(sa1 + 1);
        pw[4] = ld_a64(sa2);  pw[5] = ld_a64(sa2 + 1);
      }
    }

    // (2) MFMA own-h + x; bias folded into acc init
    f32x4 acc[4];
    #pragma unroll
    for (int gg = 0; gg < 4; ++gg)
      acc[gg] = (f32x4){bias[gg], bias[gg], bias[gg], bias[gg]};
    #pragma unroll
    for (int i = 0; i < 4; ++i){
      bf16x8 af = *(const bf16x8*)&A_s[buf][l15*AS + ktp[i]*32 + q*8];
      #pragma unroll
      for (int gg = 0; gg < 4; ++gg)
        acc[gg] = __builtin_amdgcn_mfma_f32_16x16x32_bf16(af, wfrag[i][gg], acc[gg], 0, 0, 0);
    }

    // (3) tag-check; spin. Fast mode: sc0 polls of the fast mailbox with an
    // agent-scope poll of the slow mailbox every 16th iteration (liveness
    // guaranteed independent of sc0 semantics — tag protocol absorbs stale).
    if (t > 0){
      const unsigned int need = (unsigned int)(t & 0xFFFF);
      if (fast){
        vm_wait_pw(pw);
        unsigned int it = 0;
        while (!OK6){
          ++it;
          if ((it & 15u) == 15u){
            pw[0] = ld_a64(sa0);  pw[1] = ld_a64(sa0 + 1);
            pw[2] = ld_a64(sa1);  pw[3] = ld_a64(sa1 + 1);
            pw[4] = ld_a64(sa2);  pw[5] = ld_a64(sa2 + 1);
          } else {
            ld6_wait_l2(fa0, fa1, fa2, pw);
          }
        }
      } else {
        while (!OK6){
          pw[0] = ld_a64(sa0);  pw[1] = ld_a64(sa0 + 1);
          pw[2] = ld_a64(sa1);  pw[3] = ld_a64(sa1 + 1);
          pw[4] = ld_a64(sa2);  pw[5] = ld_a64(sa2 + 1);
        }
      }
      // scatter partner h into A_s[buf] partner cols (one ds_write_b64 each)
      const int row = tid >> 4, u0c = (tid & 15) * 4;
      #pragma unroll
      for (int j = 0; j < 3; ++j){
        u64 a = pw[2*j], b = pw[2*j + 1];
        u64 hv = ((a >> 16) & 0xFFFFull)
               | (((a >> 48) & 0xFFFFull) << 16)
               | (((b >> 16) & 0xFFFFull) << 32)
               | (((b >> 48) & 0xFFFFull) << 48);
        *(u64*)&A_s[buf][row*AS + plist[j]*64 + u0c] = hv;
      }
    }
    // stage x_{t+1}
    if (tid < 128 && (t+1) < Tn){
      int m = tid >> 3, ch = tid & 7;
      *(ushort8*)&A_s[nbuf][m*AS + Un + ch*8] = *(ushort8*)xv;
    }
    __syncthreads();   // barrier A: partner cols + staged x visible

    // (4) MFMA partner-h
    if (t > 0){
      #pragma unroll
      for (int i = 4; i < 10; ++i){
        bf16x8 af = *(const bf16x8*)&A_s[buf][l15*AS + ktp[i]*32 + q*8];
        #pragma unroll
        for (int gg = 0; gg < 4; ++gg)
          acc[gg] = __builtin_amdgcn_mfma_f32_16x16x32_bf16(af, wfrag[i][gg], acc[gg], 0, 0, 0);
      }
    }

    // (5) gates; own h to LDS; publish tagged words to BOTH mailboxes.
    // Plain store -> producer-local (shared if co-located) L2, read by sc0
    // polls. Agent store -> LLC, read by slow/insurance polls + epilogue.
    {
      const unsigned int tag = (unsigned int)((t+1) & 0xFFFF);
      unsigned int* dslow = xc_slow + (size_t)nbuf*1024;
      unsigned int* dfast = xc_fast + (size_t)nbuf*1024;
      #pragma unroll
      for (int r = 0; r < 4; ++r){
        float ig = sigm(acc[0][r]);
        float fg = sigm(acc[1][r]);
        float gg = tanh_f(acc[2][r]);
        float og = sigm(acc[3][r]);
        float cn = fg * c[r] + ig * gg;
        c[r] = cn;
        unsigned short hb = f2bf(og * tanh_f(cn));
        A_s[nbuf][(q*4 + r)*AS + (s*64 + u_loc)] = hb;
        unsigned int word = ((unsigned int)hb << 16) | tag;
        int idx = (q*4 + r)*64 + u_loc;
        dfast[idx] = word;
        __hip_atomic_store(dslow + idx, word,
                           __ATOMIC_RELAXED, __HIP_MEMORY_SCOPE_AGENT);
      }
    }
    __syncthreads();   // barrier B: A_s[nbuf] own+x ready for next step
  }

  // ---- epilogue: slice-0 blocks assemble h_T, dot, write out (slow path) ----
  if (s == 0){
    const unsigned int need = (unsigned int)(Tn & 0xFFFF);
    u64 pw[6];
    pw[0] = ld_a64(pas[0]);  pw[1] = ld_a64(pas[0] + 1);
    pw[2] = ld_a64(pas[1]);  pw[3] = ld_a64(pas[1] + 1);
    pw[4] = ld_a64(pas[2]);  pw[5] = ld_a64(pas[2] + 1);
    while (!OK6){
      pw[0] = ld_a64(pas[0]);  pw[1] = ld_a64(pas[0] + 1);
      pw[2] = ld_a64(pas[1]);  pw[3] = ld_a64(pas[1] + 1);
      pw[4] = ld_a64(pas[2]);  pw[5] = ld_a64(pas[2] + 1);
    }
    const int row = tid >> 4, u0c = (tid & 15) * 4;
    #pragma unroll
    for (int j = 0; j < 3; ++j){
      u64 a = pw[2*j], b = pw[2*j + 1];
      u64 hv = ((a >> 16) & 0xFFFFull)
             | (((a >> 48) & 0xFFFFull) << 16)
             | (((b >> 16) & 0xFFFFull) << 32)
             | (((b >> 48) & 0xFFFFull) << 48);
      *(u64*)&A_s[0][row*AS + plist[j]*64 + u0c] = hv;
    }
    __syncthreads();

    int m = tid >> 4, j16 = tid & 15;
    float partial = 0.f;
    for (int u = j16; u < 256; u += 16)
      partial += bf2f(A_s[0][m*AS + u]) * load_f(dense_w, u, isf32);
    #pragma unroll
    for (int off = 1; off < 16; off <<= 1) partial += __shfl_xor(partial, off);
    if (j16 == 0) outv[m] = sigm(partial + load_f(dense_b, 0, isf32));
    __syncthreads();

    for (int mm = 0; mm < 16; ++mm){
      float v = outv[mm];
      long base = (long)(g*16 + mm) * Tn;
      for (int col = tid; col < Tn; col += THREADS){
        if (isf32) ((float*)out)[base + col] = v;
        else       ((unsigned short*)out)[base + col] = f2bf(v);
      }
    }
  }
}

// ---------------------------------------------------------------------------
extern "C" void kernel_launch(void* const* d_in, const int* in_sizes, int n_in,
                              void* d_out, int out_size, void* d_ws, size_t ws_size,
                              hipStream_t stream){
  const void* x  = d_in[0];
  const void* W  = d_in[1];
  const void* Uh = d_in[2];
  const void* b  = d_in[3];
  const void* dw = d_in[4];
  const void* db = d_in[5];

  int* hdr = (int*)d_ws;
  unsigned int* xchg = (unsigned int*)((char*)d_ws + WS_XCHG);
  unsigned short* Bp = (unsigned short*)((char*)d_ws + WS_BP);
  unsigned int* xf   = (unsigned int*)((char*)d_ws + WS_XF);

  init_k<<<1, 128, 0, stream>>>(x, hdr);
  reformat_w<<<160, 256, 0, stream>>>(Uh, W, Bp, hdr);
  lstm_k<<<NB, THREADS, 0, stream>>>(x, b, dw, db, Bp, hdr, xchg, xf, d_out);
}

// Round 3
// 2912.652 us; speedup vs baseline: 1.7327x; 1.7327x over previous
//
#include <hip/hip_runtime.h>

#define Tn 1024
#define Fn 64
#define Un 256
#define Gn 1024
#define AS 328       // padded A row stride (ushorts)
#define THREADS 256
#define NB 128       // lstm blocks

typedef __attribute__((ext_vector_type(8))) short bf16x8;
typedef __attribute__((ext_vector_type(8))) unsigned short ushort8;
typedef __attribute__((ext_vector_type(4))) float f32x4;
typedef unsigned long long u64;

// ws layout (bytes):
//   [0, 4096)            : int hdr — [0]=dtype flag, [1]=launch counter,
//                          [32..159]=per-block XCD slots (launch-tagged)
//   [WS_XCHG, +1048576)  : SLOW mailbox — NB x 2 parity x 1024 tagged u32,
//                          agent-scope atomics (the proven LLC path)
//   [WS_BP,  +655360)    : packed weights Bp
//   [WS_XF,  +1048576)   : FAST mailbox — same layout, accessed ONLY with
//                          L2-executed atomics (same-XCD shared-L2 path)
#define WS_XCHG 4096
#define WS_BP   (WS_XCHG + NB*2*4096)
#define WS_XF   (WS_BP + 655360)

__device__ __forceinline__ float bf2f(unsigned short u){
  union { unsigned int i; float f; } v; v.i = ((unsigned int)u) << 16; return v.f;
}
__device__ __forceinline__ unsigned short f2bf(float f){
  unsigned int u = __float_as_uint(f);
  u += 0x7FFFu + ((u >> 16) & 1u);
  return (unsigned short)(u >> 16);
}
__device__ __forceinline__ float load_f(const void* p, long idx, int isf32){
  if (isf32) return ((const float*)p)[idx];
  return bf2f(((const unsigned short*)p)[idx]);
}
__device__ __forceinline__ float sigm(float x){ return 1.0f / (1.0f + __expf(-x)); }
__device__ __forceinline__ float tanh_f(float x){ return 2.0f * sigm(2.0f * x) - 1.0f; }

__device__ __forceinline__ u64 ld_a64(const u64* p){
  return __hip_atomic_load(p, __ATOMIC_RELAXED, __HIP_MEMORY_SCOPE_AGENT);
}
__device__ __forceinline__ int ok64(u64 v, unsigned int need){
  return (int)(((unsigned int)v & 0xFFFFu) == need) &
         (int)(((unsigned int)(v >> 32) & 0xFFFFu) == need);
}

// ---------------------------------------------------------------------------
// Fast-mailbox primitives. KEY PROPERTY: vector-memory ATOMICS execute in the
// TCC (the XCD-shared L2), never in the CU's L1 — there are no L1 atomic
// units. Without sc1 they stay AT the local L2 (sc1 would forward them to the
// device point of coherence = the slow LLC path). So producer atomic_swap and
// consumer atomic_or(0) are guaranteed to meet in the same physical L2 when
// the blocks are co-located on one XCD (runtime consensus below).
// Round-2 post-mortem: plain store + sc0 load was stale at CU level — only
// the 1/16 agent insurance polls made progress (quantum ~3700cy, 1.8x slower).

// issue 6 poll-atomics (return-old via sc0). Inline asm: the compiler cannot
// fold the idempotent or-0 into a plain load, and cannot reorder the issue.
// NOTE: compiler does NOT track inline-asm vmcnt — vm_wait_pw must follow
// before the results are consumed.
__device__ __forceinline__ void at6_issue(const u64* a0, const u64* a1,
                                          const u64* a2, u64* pw){
  const u64 z = 0;
  asm volatile(
    "global_atomic_or_x2 %0, %6, %12, off sc0\n\t"
    "global_atomic_or_x2 %1, %7, %12, off sc0\n\t"
    "global_atomic_or_x2 %2, %8, %12, off sc0\n\t"
    "global_atomic_or_x2 %3, %9, %12, off sc0\n\t"
    "global_atomic_or_x2 %4, %10, %12, off sc0\n\t"
    "global_atomic_or_x2 %5, %11, %12, off sc0"
    : "=&v"(pw[0]), "=&v"(pw[1]), "=&v"(pw[2]),
      "=&v"(pw[3]), "=&v"(pw[4]), "=&v"(pw[5])
    : "v"(a0), "v"(a0+1), "v"(a1), "v"(a1+1), "v"(a2), "v"(a2+1), "v"(z)
    : "memory");
}
// same, but with the wait fused (spin-loop body)
__device__ __forceinline__ void at6_wait(const u64* a0, const u64* a1,
                                         const u64* a2, u64* pw){
  const u64 z = 0;
  asm volatile(
    "global_atomic_or_x2 %0, %6, %12, off sc0\n\t"
    "global_atomic_or_x2 %1, %7, %12, off sc0\n\t"
    "global_atomic_or_x2 %2, %8, %12, off sc0\n\t"
    "global_atomic_or_x2 %3, %9, %12, off sc0\n\t"
    "global_atomic_or_x2 %4, %10, %12, off sc0\n\t"
    "global_atomic_or_x2 %5, %11, %12, off sc0\n\t"
    "s_waitcnt vmcnt(0)"
    : "=&v"(pw[0]), "=&v"(pw[1]), "=&v"(pw[2]),
      "=&v"(pw[3]), "=&v"(pw[4]), "=&v"(pw[5])
    : "v"(a0), "v"(a0+1), "v"(a1), "v"(a1+1), "v"(a2), "v"(a2+1), "v"(z)
    : "memory");
}
// wait with the polled words as tied operands: the tag checks become
// data-dependent on this asm, so the compiler cannot hoist them above it.
__device__ __forceinline__ void vm_wait_pw(u64* pw){
  asm volatile("s_waitcnt vmcnt(0)"
    : "+v"(pw[0]), "+v"(pw[1]), "+v"(pw[2]),
      "+v"(pw[3]), "+v"(pw[4]), "+v"(pw[5]));
}
// producer fast-publish: RMW executed at the local L2, no return, no sc bits
__device__ __forceinline__ void at_swap_l2(unsigned int* p, unsigned int v){
  asm volatile("global_atomic_swap %0, %1, off" :: "v"(p), "v"(v) : "memory");
}

#define OK6 (ok64(pw[0], need) & ok64(pw[1], need) & ok64(pw[2], need) & \
             ok64(pw[3], need) & ok64(pw[4], need) & ok64(pw[5], need))

// ---------------------------------------------------------------------------
__global__ void init_k(const void* x, int* wsi){
  int tid = threadIdx.x;
  if (tid < 64){
    int cnt = 0;
    for (int s2 = 0; s2 < 4; ++s2){
      float v = bf2f(((const unsigned short*)x)[tid + 64*s2]);
      if (!(fabsf(v) <= 100.0f)) cnt++;
    }
    for (int off = 32; off > 0; off >>= 1) cnt += __shfl_down(cnt, off);
    if (tid == 0) wsi[0] = (cnt > 32) ? 1 : 0;   // 1 => inputs are fp32
  }
  if (tid == 0) wsi[1] = wsi[1] + 1;   // launch counter (graph replays too)
  if (tid < NB) wsi[32 + tid] = 0;     // hygiene-zero XCD slots
}

// ---------------------------------------------------------------------------
// pack [Uh; W] (K=320 x 1024) into B-fragment order. 4-way split permutation:
//   packed n: s=n>>8, w=(n>>6)&3, g=(n>>4)&3, ul=n&15
//   -> orig col = g*256 + s*64 + w*16 + ul
__global__ void reformat_w(const void* Uh, const void* W, unsigned short* Bp, const int* dt){
  int isf32 = *dt;
  int gidx = blockIdx.x * blockDim.x + threadIdx.x;
  if (gidx >= 40960) return;
  int kt  = gidx >> 12;
  int rem = gidx & 4095;
  int n   = rem >> 2;
  int q   = rem & 3;
  int s   = n >> 8;
  int w   = (n >> 6) & 3;
  int g   = (n >> 4) & 3;
  int ul  = n & 15;
  int col = g*256 + s*64 + w*16 + ul;
  unsigned short vals[8];
  #pragma unroll
  for (int j = 0; j < 8; ++j){
    int k = kt*32 + q*8 + j;
    float v = (k < Un) ? load_f(Uh, (long)k*Gn + col, isf32)
                       : load_f(W,  (long)(k-Un)*Gn + col, isf32);
    vals[j] = f2bf(v);
  }
  *(ushort8*)(Bp + (long)gidx * 8) = *(ushort8*)vals;
}

// ---------------------------------------------------------------------------
// Persistent LSTM, 128 blocks x 256 threads.
// XCD-clustered mapping: group g = bid&31, slice s = bid>>5, so a group's four
// blocks {g, g+32, g+64, g+96} are congruent mod 8 — same XCD under
// round-robin dispatch. Runtime consensus (HW_REG_XCC_ID, launch-tagged)
// selects the protocol; co-located groups exchange h via L2-executed atomics,
// others use the proven agent path. Liveness never depends on the fast path
// (periodic agent insurance polls + dual publish).
__global__ __launch_bounds__(THREADS, 1) void lstm_k(
    const void* x, const void* bvec, const void* dense_w, const void* dense_b,
    const unsigned short* Bp, int* hdr, unsigned int* xchg, unsigned int* xf,
    void* out)
{
  __shared__ __align__(16) unsigned short A_s[2][16*AS];
  __shared__ float outv[16];
  __shared__ int proto_s;

  const int isf32 = hdr[0];
  const unsigned int Lid = ((unsigned int)hdr[1]) & 0xFFFFu;
  const int tid = threadIdx.x;
  const int w   = tid >> 6;
  const int l   = tid & 63;
  const int l15 = l & 15;
  const int q   = l >> 4;
  const int g   = blockIdx.x & 31;   // group (same-XCD cluster under RR)
  const int s   = blockIdx.x >> 5;   // slice

  // publish own physical XCD id, tagged with this launch's id
  int* slots = hdr + 32;
  if (tid == 0){
    unsigned int xcc;
    asm volatile("s_getreg_b32 %0, hwreg(HW_REG_XCC_ID)" : "=s"(xcc));
    __hip_atomic_store(&slots[blockIdx.x], (int)((Lid << 16) | (xcc & 0xFFu)),
                       __ATOMIC_RELAXED, __HIP_MEMORY_SCOPE_AGENT);
  }

  int plist[3];
  #pragma unroll
  for (int j = 0; j < 3; ++j) plist[j] = j + (j >= s ? 1 : 0);

  // ---- weights into registers ----
  int ktp[10];
  ktp[0] = 2*s; ktp[1] = 2*s + 1; ktp[2] = 8; ktp[3] = 9;
  #pragma unroll
  for (int j = 0; j < 3; ++j){ ktp[4+2*j] = 2*plist[j]; ktp[5+2*j] = 2*plist[j] + 1; }

  const char* Bb = (const char*)Bp + (long)(l15*64 + q*16);
  const int nb = s*256 + w*64;
  bf16x8 wfrag[10][4];
  #pragma unroll
  for (int i = 0; i < 10; ++i){
    #pragma unroll
    for (int gg = 0; gg < 4; ++gg)
      wfrag[i][gg] = *(const bf16x8*)(Bb + (long)(ktp[i]*1024 + nb + gg*16)*64);
  }

  // zero h region of buffer 0
  for (int i = tid; i < 16*Un; i += THREADS)
    A_s[0][(i >> 8)*AS + (i & 255)] = 0;

  // x_0 -> buffer 0 cols [256,320)
  if (tid < 128){
    int m = tid >> 3, ch = tid & 7;
    long src = ((long)(g*16 + m)*Tn + 0)*Fn + ch*8;
    unsigned short v[8];
    if (isf32){ for (int j = 0; j < 8; ++j) v[j] = f2bf(((const float*)x)[src + j]); }
    else      { *(ushort8*)v = *(const ushort8*)((const unsigned short*)x + src); }
    *(ushort8*)&A_s[0][m*AS + Un + ch*8] = *(ushort8*)v;
  }

  const int u_loc = w*16 + l15;
  float bias[4];
  #pragma unroll
  for (int gg = 0; gg < 4; ++gg) bias[gg] = load_f(bvec, gg*256 + s*64 + u_loc, isf32);

  float c[4] = {0.f, 0.f, 0.f, 0.f};
  unsigned int* xc_slow = xchg + (size_t)(g*4 + s) * 2048;
  unsigned int* xc_fast = xf   + (size_t)(g*4 + s) * 2048;

  // per-thread partner poll addresses (parity offset applied per step)
  const u64* pas[3];
  const u64* paf[3];
  #pragma unroll
  for (int j = 0; j < 3; ++j){
    pas[j] = (const u64*)(xchg + (size_t)((g*4 + plist[j])*2)*1024) + tid*2;
    paf[j] = (const u64*)(xf   + (size_t)((g*4 + plist[j])*2)*1024) + tid*2;
  }

  // ---- XCD consensus: all four group members must agree (launch-tagged) ----
  if (tid == 0){
    int v0 = 0, ok = 1;
    #pragma unroll
    for (int m = 0; m < 4; ++m){
      int val;
      do {
        val = __hip_atomic_load(&slots[(m << 5) | g],
                                __ATOMIC_RELAXED, __HIP_MEMORY_SCOPE_AGENT);
      } while (((unsigned int)val >> 16) != Lid);
      if (m == 0) v0 = val; else ok &= (int)(val == v0);
    }
    proto_s = ok;   // 1 => all four blocks on one XCD => L2-atomic exchange
  }

  __syncthreads();
  const int fast = proto_s;

  for (int t = 0; t < Tn; ++t){
    const int buf = t & 1, nbuf = buf ^ 1;
    const size_t po = (size_t)buf * 512;   // parity offset in u64s
    const u64* sa0 = pas[0] + po;
    const u64* sa1 = pas[1] + po;
    const u64* sa2 = pas[2] + po;
    const u64* fa0 = paf[0] + po;
    const u64* fa1 = paf[1] + po;
    const u64* fa2 = paf[2] + po;

    // (1) x_{t+1} into regs
    unsigned short xv[8];
    if (tid < 128 && (t+1) < Tn){
      int m = tid >> 3, ch = tid & 7;
      long src = ((long)(g*16 + m)*Tn + (t+1))*Fn + ch*8;
      if (isf32){ for (int j = 0; j < 8; ++j) xv[j] = f2bf(((const float*)x)[src + j]); }
      else      { *(ushort8*)xv = *(const ushort8*)((const unsigned short*)x + src); }
    }

    // (1b) PRE-ISSUE all six partner poll-atomics (fly under the MFMA phase)
    u64 pw[6];
    if (t > 0){
      if (fast){
        at6_issue(fa0, fa1, fa2, pw);
      } else {
        pw[0] = ld_a64(sa0);  pw[1] = ld_a64(sa0 + 1);
        pw[2] = ld_a64(sa1);  pw[3] = ld_a64(sa1 + 1);
        pw[4] = ld_a64(sa2);  pw[5] = ld_a64(sa2 + 1);
      }
    }

    // (2) MFMA own-h + x; bias folded into acc init
    f32x4 acc[4];
    #pragma unroll
    for (int gg = 0; gg < 4; ++gg)
      acc[gg] = (f32x4){bias[gg], bias[gg], bias[gg], bias[gg]};
    #pragma unroll
    for (int i = 0; i < 4; ++i){
      bf16x8 af = *(const bf16x8*)&A_s[buf][l15*AS + ktp[i]*32 + q*8];
      #pragma unroll
      for (int gg = 0; gg < 4; ++gg)
        acc[gg] = __builtin_amdgcn_mfma_f32_16x16x32_bf16(af, wfrag[i][gg], acc[gg], 0, 0, 0);
    }

    // (3) tag-check; spin. Fast mode: L2-atomic polls of the fast mailbox,
    // agent-scope insurance poll of the slow mailbox every 16th iteration
    // (liveness independent of the fast path; tag protocol absorbs stale).
    if (t > 0){
      const unsigned int need = (unsigned int)(t & 0xFFFF);
      if (fast){
        vm_wait_pw(pw);
        unsigned int it = 0;
        while (!OK6){
          ++it;
          if ((it & 15u) == 15u){
            pw[0] = ld_a64(sa0);  pw[1] = ld_a64(sa0 + 1);
            pw[2] = ld_a64(sa1);  pw[3] = ld_a64(sa1 + 1);
            pw[4] = ld_a64(sa2);  pw[5] = ld_a64(sa2 + 1);
          } else {
            at6_wait(fa0, fa1, fa2, pw);
          }
        }
      } else {
        while (!OK6){
          pw[0] = ld_a64(sa0);  pw[1] = ld_a64(sa0 + 1);
          pw[2] = ld_a64(sa1);  pw[3] = ld_a64(sa1 + 1);
          pw[4] = ld_a64(sa2);  pw[5] = ld_a64(sa2 + 1);
        }
      }
      // scatter partner h into A_s[buf] partner cols (one ds_write_b64 each)
      const int row = tid >> 4, u0c = (tid & 15) * 4;
      #pragma unroll
      for (int j = 0; j < 3; ++j){
        u64 a = pw[2*j], b = pw[2*j + 1];
        u64 hv = ((a >> 16) & 0xFFFFull)
               | (((a >> 48) & 0xFFFFull) << 16)
               | (((b >> 16) & 0xFFFFull) << 32)
               | (((b >> 48) & 0xFFFFull) << 48);
        *(u64*)&A_s[buf][row*AS + plist[j]*64 + u0c] = hv;
      }
    }
    // stage x_{t+1}
    if (tid < 128 && (t+1) < Tn){
      int m = tid >> 3, ch = tid & 7;
      *(ushort8*)&A_s[nbuf][m*AS + Un + ch*8] = *(ushort8*)xv;
    }
    __syncthreads();   // barrier A: partner cols + staged x visible

    // (4) MFMA partner-h
    if (t > 0){
      #pragma unroll
      for (int i = 4; i < 10; ++i){
        bf16x8 af = *(const bf16x8*)&A_s[buf][l15*AS + ktp[i]*32 + q*8];
        #pragma unroll
        for (int gg = 0; gg < 4; ++gg)
          acc[gg] = __builtin_amdgcn_mfma_f32_16x16x32_bf16(af, wfrag[i][gg], acc[gg], 0, 0, 0);
      }
    }

    // (5) gates; own h to LDS; publish tagged words.
    // Fast mode: atomic_swap executed at the shared L2 (+ agent store to the
    // slow mailbox for insurance/epilogue). Slow mode: agent store only.
    {
      const unsigned int tag = (unsigned int)((t+1) & 0xFFFF);
      unsigned int* dslow = xc_slow + (size_t)nbuf*1024;
      unsigned int* dfast = xc_fast + (size_t)nbuf*1024;
      #pragma unroll
      for (int r = 0; r < 4; ++r){
        float ig = sigm(acc[0][r]);
        float fg = sigm(acc[1][r]);
        float gg = tanh_f(acc[2][r]);
        float og = sigm(acc[3][r]);
        float cn = fg * c[r] + ig * gg;
        c[r] = cn;
        unsigned short hb = f2bf(og * tanh_f(cn));
        A_s[nbuf][(q*4 + r)*AS + (s*64 + u_loc)] = hb;
        unsigned int word = ((unsigned int)hb << 16) | tag;
        int idx = (q*4 + r)*64 + u_loc;
        if (fast) at_swap_l2(dfast + idx, word);
        __hip_atomic_store(dslow + idx, word,
                           __ATOMIC_RELAXED, __HIP_MEMORY_SCOPE_AGENT);
      }
    }
    __syncthreads();   // barrier B: A_s[nbuf] own+x ready for next step
  }

  // ---- epilogue: slice-0 blocks assemble h_T, dot, write out (slow path) ----
  if (s == 0){
    const unsigned int need = (unsigned int)(Tn & 0xFFFF);
    u64 pw[6];
    pw[0] = ld_a64(pas[0]);  pw[1] = ld_a64(pas[0] + 1);
    pw[2] = ld_a64(pas[1]);  pw[3] = ld_a64(pas[1] + 1);
    pw[4] = ld_a64(pas[2]);  pw[5] = ld_a64(pas[2] + 1);
    while (!OK6){
      pw[0] = ld_a64(pas[0]);  pw[1] = ld_a64(pas[0] + 1);
      pw[2] = ld_a64(pas[1]);  pw[3] = ld_a64(pas[1] + 1);
      pw[4] = ld_a64(pas[2]);  pw[5] = ld_a64(pas[2] + 1);
    }
    const int row = tid >> 4, u0c = (tid & 15) * 4;
    #pragma unroll
    for (int j = 0; j < 3; ++j){
      u64 a = pw[2*j], b = pw[2*j + 1];
      u64 hv = ((a >> 16) & 0xFFFFull)
             | (((a >> 48) & 0xFFFFull) << 16)
             | (((b >> 16) & 0xFFFFull) << 32)
             | (((b >> 48) & 0xFFFFull) << 48);
      *(u64*)&A_s[0][row*AS + plist[j]*64 + u0c] = hv;
    }
    __syncthreads();

    int m = tid >> 4, j16 = tid & 15;
    float partial = 0.f;
    for (int u = j16; u < 256; u += 16)
      partial += bf2f(A_s[0][m*AS + u]) * load_f(dense_w, u, isf32);
    #pragma unroll
    for (int off = 1; off < 16; off <<= 1) partial += __shfl_xor(partial, off);
    if (j16 == 0) outv[m] = sigm(partial + load_f(dense_b, 0, isf32));
    __syncthreads();

    for (int mm = 0; mm < 16; ++mm){
      float v = outv[mm];
      long base = (long)(g*16 + mm) * Tn;
      for (int col = tid; col < Tn; col += THREADS){
        if (isf32) ((float*)out)[base + col] = v;
        else       ((unsigned short*)out)[base + col] = f2bf(v);
      }
    }
  }
}

// ---------------------------------------------------------------------------
extern "C" void kernel_launch(void* const* d_in, const int* in_sizes, int n_in,
                              void* d_out, int out_size, void* d_ws, size_t ws_size,
                              hipStream_t stream){
  const void* x  = d_in[0];
  const void* W  = d_in[1];
  const void* Uh = d_in[2];
  const void* b  = d_in[3];
  const void* dw = d_in[4];
  const void* db = d_in[5];

  int* hdr = (int*)d_ws;
  unsigned int* xchg = (unsigned int*)((char*)d_ws + WS_XCHG);
  unsigned short* Bp = (unsigned short*)((char*)d_ws + WS_BP);
  unsigned int* xf   = (unsigned int*)((char*)d_ws + WS_XF);

  init_k<<<1, 128, 0, stream>>>(x, hdr);
  reformat_w<<<160, 256, 0, stream>>>(Uh, W, Bp, hdr);
  lstm_k<<<NB, THREADS, 0, stream>>>(x, b, dw, db, Bp, hdr, xchg, xf, d_out);
}

// Round 4
// 2803.422 us; speedup vs baseline: 1.8003x; 1.0390x over previous
//
#include <hip/hip_runtime.h>

#define Tn 1024
#define Fn 64
#define Un 256
#define Gn 1024
#define AS 328       // padded A row stride (ushorts)
#define THREADS 512
#define NB 64        // lstm blocks (2-way split: 32 groups x 2 slices)

typedef __attribute__((ext_vector_type(8))) short bf16x8;
typedef __attribute__((ext_vector_type(8))) unsigned short ushort8;
typedef __attribute__((ext_vector_type(4))) float f32x4;
typedef unsigned long long u64;

// ws layout (bytes):
//   [0, 4096)            : int hdr — [0]=dtype flag
//   [WS_XCHG, +1048576)  : xchg — NB x 2 parity x 2048 tagged u32
//                          (value = bf16<<16 | step-tag), agent-scope
//   [WS_BP,  +655360)    : packed weights Bp
#define WS_XCHG 4096
#define WS_BP   (WS_XCHG + NB*2*8192)

__device__ __forceinline__ float bf2f(unsigned short u){
  union { unsigned int i; float f; } v; v.i = ((unsigned int)u) << 16; return v.f;
}
__device__ __forceinline__ unsigned short f2bf(float f){
  unsigned int u = __float_as_uint(f);
  u += 0x7FFFu + ((u >> 16) & 1u);
  return (unsigned short)(u >> 16);
}
__device__ __forceinline__ float load_f(const void* p, long idx, int isf32){
  if (isf32) return ((const float*)p)[idx];
  return bf2f(((const unsigned short*)p)[idx]);
}
__device__ __forceinline__ float sigm(float x){ return 1.0f / (1.0f + __expf(-x)); }
__device__ __forceinline__ float tanh_f(float x){ return 2.0f * sigm(2.0f * x) - 1.0f; }

__device__ __forceinline__ u64 ld_a64(const u64* p){
  return __hip_atomic_load(p, __ATOMIC_RELAXED, __HIP_MEMORY_SCOPE_AGENT);
}
__device__ __forceinline__ int ok64(u64 v, unsigned int need){
  return (int)(((unsigned int)v & 0xFFFFu) == need) &
         (int)(((unsigned int)(v >> 32) & 0xFFFFu) == need);
}
// pack 4 tagged words (2 u64) into 4 bf16 h values
__device__ __forceinline__ u64 pack_h(u64 a, u64 b){
  return ((a >> 16) & 0xFFFFull)
       | (((a >> 48) & 0xFFFFull) << 16)
       | (((b >> 16) & 0xFFFFull) << 32)
       | (((b >> 48) & 0xFFFFull) << 48);
}

// ---------------------------------------------------------------------------
__global__ void init_k(const void* x, int* wsi){
  int tid = threadIdx.x;
  if (tid < 64){
    int cnt = 0;
    for (int s2 = 0; s2 < 4; ++s2){
      float v = bf2f(((const unsigned short*)x)[tid + 64*s2]);
      if (!(fabsf(v) <= 100.0f)) cnt++;
    }
    for (int off = 32; off > 0; off >>= 1) cnt += __shfl_down(cnt, off);
    if (tid == 0) wsi[0] = (cnt > 32) ? 1 : 0;   // 1 => inputs are fp32
  }
}

// ---------------------------------------------------------------------------
// pack [Uh; W] (K=320 x 1024) into B-fragment order for the 2-way split:
//   packed n: s=n>>9, w=(n>>6)&7, g=(n>>4)&3, ul=n&15
//   -> orig col = g*256 + s*128 + w*16 + ul
__global__ void reformat_w(const void* Uh, const void* W, unsigned short* Bp, const int* dt){
  int isf32 = *dt;
  int gidx = blockIdx.x * blockDim.x + threadIdx.x;
  if (gidx >= 40960) return;
  int kt  = gidx >> 12;
  int rem = gidx & 4095;
  int n   = rem >> 2;
  int q   = rem & 3;
  int s   = n >> 9;
  int w   = (n >> 6) & 7;
  int g   = (n >> 4) & 3;
  int ul  = n & 15;
  int col = g*256 + s*128 + w*16 + ul;
  unsigned short vals[8];
  #pragma unroll
  for (int j = 0; j < 8; ++j){
    int k = kt*32 + q*8 + j;
    float v = (k < Un) ? load_f(Uh, (long)k*Gn + col, isf32)
                       : load_f(W,  (long)(k-Un)*Gn + col, isf32);
    vals[j] = f2bf(v);
  }
  *(ushort8*)(Bp + (long)gidx * 8) = *(ushort8*)vals;
}

// ---------------------------------------------------------------------------
// Persistent LSTM, 64 blocks x 512 threads (2-way split).
// Group g = bid>>1 (16 batch rows), slice s = bid&1 (units s*128..+128, all
// 4 gates). Partner = bid^1: ONE exchange partner instead of three —
// removes max-of-3 skew, halves the poll storm (which round-2/3 showed
// couples directly into the visibility RT). Weights VGPR-resident
// (wfrag[10][4] per wave, 8 waves). Exchange: proven tag-in-data agent-scope
// protocol (rounds 1-3 established all cross-CU paths have the same RT; the
// exotic mechanisms are removed). s_sleep backoff damps spin congestion.
__global__ __launch_bounds__(THREADS, 2) void lstm_k(
    const void* x, const void* bvec, const void* dense_w, const void* dense_b,
    const unsigned short* Bp, const int* dt, unsigned int* xchg, void* out)
{
  __shared__ __align__(16) unsigned short A_s[2][16*AS];
  __shared__ float outv[16];

  const int isf32 = *dt;
  const int tid = threadIdx.x;
  const int w   = tid >> 6;        // wave 0..7
  const int l   = tid & 63;
  const int l15 = l & 15;
  const int q   = l >> 4;
  const int g   = blockIdx.x >> 1;
  const int s   = blockIdx.x & 1;
  const int sp  = s ^ 1;

  // k-tile order: own h slice (4 tiles) + x (2 tiles) first, partner last
  int ktp[10];
  ktp[0] = 4*s;  ktp[1] = 4*s+1;  ktp[2] = 4*s+2;  ktp[3] = 4*s+3;
  ktp[4] = 8;    ktp[5] = 9;
  ktp[6] = 4*sp; ktp[7] = 4*sp+1; ktp[8] = 4*sp+2; ktp[9] = 4*sp+3;

  // ---- weights into registers ----
  const char* Bb = (const char*)Bp + (long)(l15*64 + q*16);
  const int nb = s*512 + w*64;
  bf16x8 wfrag[10][4];
  #pragma unroll
  for (int i = 0; i < 10; ++i){
    #pragma unroll
    for (int gg = 0; gg < 4; ++gg)
      wfrag[i][gg] = *(const bf16x8*)(Bb + (long)(ktp[i]*1024 + nb + gg*16)*64);
  }

  // zero h region of buffer 0
  for (int i = tid; i < 16*Un; i += THREADS)
    A_s[0][(i >> 8)*AS + (i & 255)] = 0;

  // x_0 -> buffer 0 cols [256,320)
  if (tid < 128){
    int m = tid >> 3, ch = tid & 7;
    long src = ((long)(g*16 + m)*Tn + 0)*Fn + ch*8;
    unsigned short v[8];
    if (isf32){ for (int j = 0; j < 8; ++j) v[j] = f2bf(((const float*)x)[src + j]); }
    else      { *(ushort8*)v = *(const ushort8*)((const unsigned short*)x + src); }
    *(ushort8*)&A_s[0][m*AS + Un + ch*8] = *(ushort8*)v;
  }

  const int u_loc = w*16 + l15;    // 0..127 within own slice
  float bias[4];
  #pragma unroll
  for (int gg = 0; gg < 4; ++gg) bias[gg] = load_f(bvec, gg*256 + s*128 + u_loc, isf32);

  float c[4] = {0.f, 0.f, 0.f, 0.f};
  unsigned int* xc_me = xchg + (size_t)blockIdx.x * 4096;
  const u64* pa = (const u64*)(xchg + (size_t)(blockIdx.x ^ 1) * 4096) + tid*2;

  __syncthreads();

  for (int t = 0; t < Tn; ++t){
    const int buf = t & 1, nbuf = buf ^ 1;
    const size_t po = (size_t)buf * 1024;   // parity offset in u64s

    // (1) x_{t+1} into regs
    unsigned short xv[8];
    if (tid < 128 && (t+1) < Tn){
      int m = tid >> 3, ch = tid & 7;
      long src = ((long)(g*16 + m)*Tn + (t+1))*Fn + ch*8;
      if (isf32){ for (int j = 0; j < 8; ++j) xv[j] = f2bf(((const float*)x)[src + j]); }
      else      { *(ushort8*)xv = *(const ushort8*)((const unsigned short*)x + src); }
    }

    // (1b) PRE-ISSUE partner tag-loads (fly under the own-MFMA phase)
    u64 pw0 = 0, pw1 = 0;
    if (t > 0){
      pw0 = ld_a64(pa + po);
      pw1 = ld_a64(pa + po + 1);
    }

    // (2) MFMA own-h + x (6 k-tiles); bias folded into acc init
    f32x4 acc[4];
    #pragma unroll
    for (int gg = 0; gg < 4; ++gg)
      acc[gg] = (f32x4){bias[gg], bias[gg], bias[gg], bias[gg]};
    #pragma unroll
    for (int i = 0; i < 6; ++i){
      bf16x8 af = *(const bf16x8*)&A_s[buf][l15*AS + ktp[i]*32 + q*8];
      #pragma unroll
      for (int gg = 0; gg < 4; ++gg)
        acc[gg] = __builtin_amdgcn_mfma_f32_16x16x32_bf16(af, wfrag[i][gg], acc[gg], 0, 0, 0);
    }

    // (3) tag-check; spin with s_sleep backoff (damp the poll storm so the
    // partner's publish stores aren't queued behind our own polls)
    if (t > 0){
      const unsigned int need = (unsigned int)(t & 0xFFFF);
      int first = 1;
      while (!(ok64(pw0, need) & ok64(pw1, need))){
        if (!first) __builtin_amdgcn_s_sleep(1);
        first = 0;
        pw0 = ld_a64(pa + po);
        pw1 = ld_a64(pa + po + 1);
      }
      // scatter partner h into A_s[buf] partner cols (one ds_write_b64)
      const int row = tid >> 5, col = (tid & 31) * 4;
      *(u64*)&A_s[buf][row*AS + sp*128 + col] = pack_h(pw0, pw1);
    }
    // stage x_{t+1}
    if (tid < 128 && (t+1) < Tn){
      int m = tid >> 3, ch = tid & 7;
      *(ushort8*)&A_s[nbuf][m*AS + Un + ch*8] = *(ushort8*)xv;
    }
    __syncthreads();   // barrier A: partner cols + staged x visible

    // (4) MFMA partner-h (4 k-tiles)
    if (t > 0){
      #pragma unroll
      for (int i = 6; i < 10; ++i){
        bf16x8 af = *(const bf16x8*)&A_s[buf][l15*AS + ktp[i]*32 + q*8];
        #pragma unroll
        for (int gg = 0; gg < 4; ++gg)
          acc[gg] = __builtin_amdgcn_mfma_f32_16x16x32_bf16(af, wfrag[i][gg], acc[gg], 0, 0, 0);
      }
    }

    // (5) gates; own h to LDS; publish tagged words (agent scope)
    {
      const unsigned int tag = (unsigned int)((t+1) & 0xFFFF);
      unsigned int* dstb = xc_me + (size_t)nbuf*2048;
      #pragma unroll
      for (int r = 0; r < 4; ++r){
        float ig = sigm(acc[0][r]);
        float fg = sigm(acc[1][r]);
        float gg = tanh_f(acc[2][r]);
        float og = sigm(acc[3][r]);
        float cn = fg * c[r] + ig * gg;
        c[r] = cn;
        unsigned short hb = f2bf(og * tanh_f(cn));
        A_s[nbuf][(q*4 + r)*AS + (s*128 + u_loc)] = hb;
        __hip_atomic_store(dstb + (q*4 + r)*128 + u_loc,
                           ((unsigned int)hb << 16) | tag,
                           __ATOMIC_RELAXED, __HIP_MEMORY_SCOPE_AGENT);
      }
    }
    __syncthreads();   // barrier B: A_s[nbuf] own+x ready for next step
  }

  // ---- epilogue: slice-0 blocks assemble h_T, dot, write out ----
  if (s == 0){
    const unsigned int need = (unsigned int)(Tn & 0xFFFF);
    u64 pw0 = ld_a64(pa), pw1 = ld_a64(pa + 1);
    while (!(ok64(pw0, need) & ok64(pw1, need))){
      __builtin_amdgcn_s_sleep(1);
      pw0 = ld_a64(pa);
      pw1 = ld_a64(pa + 1);
    }
    const int row = tid >> 5, col = (tid & 31) * 4;
    *(u64*)&A_s[0][row*AS + 128 + col] = pack_h(pw0, pw1);
    __syncthreads();

    int m = tid >> 5, j = tid & 31;
    float partial = 0.f;
    for (int u = j; u < 256; u += 32)
      partial += bf2f(A_s[0][m*AS + u]) * load_f(dense_w, u, isf32);
    #pragma unroll
    for (int off = 1; off < 32; off <<= 1) partial += __shfl_xor(partial, off);
    if (j == 0) outv[m] = sigm(partial + load_f(dense_b, 0, isf32));
    __syncthreads();

    for (int mm = 0; mm < 16; ++mm){
      float v = outv[mm];
      long base = (long)(g*16 + mm) * Tn;
      for (int col2 = tid; col2 < Tn; col2 += THREADS){
        if (isf32) ((float*)out)[base + col2] = v;
        else       ((unsigned short*)out)[base + col2] = f2bf(v);
      }
    }
  }
}

// ---------------------------------------------------------------------------
extern "C" void kernel_launch(void* const* d_in, const int* in_sizes, int n_in,
                              void* d_out, int out_size, void* d_ws, size_t ws_size,
                              hipStream_t stream){
  const void* x  = d_in[0];
  const void* W  = d_in[1];
  const void* Uh = d_in[2];
  const void* b  = d_in[3];
  const void* dw = d_in[4];
  const void* db = d_in[5];

  int* hdr = (int*)d_ws;
  unsigned int* xchg = (unsigned int*)((char*)d_ws + WS_XCHG);
  unsigned short* Bp = (unsigned short*)((char*)d_ws + WS_BP);

  init_k<<<1, 64, 0, stream>>>(x, hdr);
  reformat_w<<<160, 256, 0, stream>>>(Uh, W, Bp, hdr);
  lstm_k<<<NB, THREADS, 0, stream>>>(x, b, dw, db, Bp, hdr, xchg, d_out);
}